// Round 3
// baseline (149.247 us; speedup 1.0000x reference)
//
#include <hip/hip_runtime.h>
#include <math.h>

#define NROWS 16384
#define DT_C 0.01f

typedef short s16x8 __attribute__((ext_vector_type(8)));
typedef float f32x4 __attribute__((ext_vector_type(4)));
typedef float f32x2 __attribute__((ext_vector_type(2)));
typedef unsigned long long u64;
typedef unsigned long long u64x2 __attribute__((ext_vector_type(2)));

__device__ __forceinline__ unsigned short f2bf(float f) {
    unsigned u = __float_as_uint(f);
    u += 0x7fffu + ((u >> 16) & 1u);
    return (unsigned short)(u >> 16);
}
__device__ __forceinline__ unsigned pack2bf(float a, float b) {
    return (unsigned)f2bf(a) | ((unsigned)f2bf(b) << 16);
}
// VALU-pipe cross-lane adds via DPP. 16-lane sum:
// xor1 (0xB1), xor2 (0x4E), row_half_mirror (0x141), row_mirror (0x140).
template <int CTRL>
__device__ __forceinline__ float dppadd(float v) {
    int x = __builtin_amdgcn_update_dpp(0, __float_as_int(v), CTRL, 0xF, 0xF, true);
    return v + __int_as_float(x);
}
__device__ __forceinline__ float sum16(float p) {
    p = dppadd<0xB1>(p);
    p = dppadd<0x4E>(p);
    p = dppadd<0x141>(p);
    p = dppadd<0x140>(p);
    return p;
}
// total-order key transform for f32 (monotone bijection to uint)
__device__ __forceinline__ unsigned ordf(float f) {
    unsigned u = __float_as_uint(f);
    return u ^ ((unsigned)((int)u >> 31) | 0x80000000u);
}

// ---------------------------------------------------------------------------
// Prep: pack stage-B weights to bf16 flat [stage][k8][n][8] (k = k8*8+j).
// s=0: W_feat1[0:256], s=1: W_feat2, s=2: [W_xim1 | W_xil1].
// ---------------------------------------------------------------------------
__global__ __launch_bounds__(256) void prep_k(
    const float* __restrict__ Wf1, const float* __restrict__ Wf2,
    const float* __restrict__ Wm1, const float* __restrict__ Wl1,
    const float* __restrict__ bm1, const float* __restrict__ bl1,
    unsigned short* __restrict__ wpack, float* __restrict__ biasH)
{
    const int id = blockIdx.x * 256 + threadIdx.x;   // 0..24575
    const int n  = id & 255;
    const int k8 = (id >> 8) & 31;
    const int s  = id >> 13;

    unsigned short tmp[8];
    #pragma unroll
    for (int j = 0; j < 8; ++j) {
        const int k = k8 * 8 + j;
        float v;
        if (s == 0)      v = Wf1[k * 256 + n];
        else if (s == 1) v = Wf2[k * 256 + n];
        else             v = (n < 128) ? Wm1[k * 128 + n] : Wl1[k * 128 + n - 128];
        tmp[j] = f2bf(v);
    }
    *(uint4*)&wpack[((s * 32 + k8) * 256 + n) * 8] = *(const uint4*)tmp;

    if (id < 256) biasH[id] = (id < 128) ? bm1[id] : bl1[id - 128];
}

// ---------------------------------------------------------------------------
// Fused kernel, 512 threads (8 waves) per 32-row block:
//   stage data->LDS frags + exact piecewise-linear (PWL) tables of the aux
//   MLP acc(y) = A_k + B_k*y (64 breakpoints, rank-sorted, 16 lanes/row);
//   MFMA h1->feat->heads with per-stage register B-prefetch;
//   per-row 128-dots -> xi; then waves 1..7 RETURN and wave 0 alone runs the
//   PWL ODE scan (1 lane/row, 32 lanes), decay fused into the single write.
// ---------------------------------------------------------------------------
__global__ __launch_bounds__(512, 4) void fused_k(
    const float* __restrict__ data, const float* __restrict__ omega,
    const float* __restrict__ eps_g,
    const unsigned short* __restrict__ wpack, const float* __restrict__ biasH,
    const float* __restrict__ bf1, const float* __restrict__ bf2,
    const float* __restrict__ w256g,
    const float* __restrict__ Wm2, const float* __restrict__ bm2,
    const float* __restrict__ Wl2, const float* __restrict__ bl2,
    const float* __restrict__ Wa1, const float* __restrict__ ba1,
    const float* __restrict__ Wa2, const float* __restrict__ ba2,
    float* __restrict__ out_mean, float* __restrict__ out_lnvar,
    float* __restrict__ xout)
{
    // 58.25KB LDS: headsF aliases As1+Hs (dead by heads phase);
    // keyU aliases dP (keys dead after sort). 2 blocks/CU -> 116.5KB/CU.
    __shared__ __align__(16) unsigned char smem[59648];
    unsigned short* As1 = (unsigned short*)smem;            // 16KB frags: data, then feat
    unsigned short* Hs  = (unsigned short*)(smem + 16384);  // 16KB frags: h1
    float* headsF = (float*)smem;                           // 32KB alias: heads f32
    float* omg = (float*)(smem + 32768);
    float* xiS = omg + 32;
    float* tS  = (float*)(smem + 33024);                    // [32][68] sorted t (+/-inf pads)
    float* dP  = (float*)(smem + 41728);                    // [32][68] float2 (dA,dB)
    u64*  keyU = (u64*)(smem + 41728);                      // alias: [32][66] sort keys (padded)
    float* initS = (float*)(smem + 59136);                  // [32] float4 {y0,k0,A0,B0}

    const int tid  = threadIdx.x;
    const int wid  = tid >> 6;          // 0..7
    const int lane = tid & 63;
    const int ln   = lane & 15;
    const int quad = lane >> 4;
    const int r0   = blockIdx.x * 32;

    // ---- stage data -> As1 (coalesced, swizzled frag pack)
    {
        #pragma unroll
        for (int g2 = 0; g2 < 4; ++g2) {
            const int unit = g2 * 512 + tid;     // 16B unit over 32x256 f32
            const int m    = unit >> 6;
            const int c16  = unit & 63;
            const int kblk = c16 >> 1;
            const int h    = c16 & 1;
            const float4 v = *(const float4*)&data[(size_t)(r0 + m) * 256 + c16 * 4];
            unsigned* d = (unsigned*)&As1[((kblk * 32) + (m ^ (kblk & 7))) * 8 + h * 4];
            d[0] = pack2bf(v.x, v.y);
            d[1] = pack2bf(v.z, v.w);
        }
        if (tid < 32) omg[tid] = omega[r0 + tid];
    }

    // ---- PWL setup part A (VALU overlaps staging loads), 16 lanes/row:
    // unit i active <=> a_i + w_i*y > 0; breakpoint t_i = -a_i/w_i.
    // Crossing t_i upward: delta (dA,dB) = sgn(w_i)*(c_i*a_i, c_i*w_i).
    const int sr = tid >> 4;      // row 0..31
    const int sl = tid & 15;      // 16 lanes/row, units i = sl*4+m
    float tA[4], dAv[4], dBv[4];
    u64 key[4];
    {
        const float om_s = omega[r0 + sr];
        const float y0_s = data[(size_t)(r0 + sr) * 256];
        const u64 ky0 = ((u64)ordf(y0_s)) << 6;
        float k0p = 0.f, Ap = 0.f, Bp = 0.f;
        #pragma unroll
        for (int m = 0; m < 4; ++m) {
            const int i = sl * 4 + m;
            const float a = fmaf(om_s, Wa1[i], ba1[i]);
            const float w = Wa1[64 + i];
            const float c = Wa2[i];
            const float ca = c * a, cw = c * w;
            const bool wpos = w > 0.f;
            tA[m]  = -a / w;
            dAv[m] = wpos ? ca : -ca;
            dBv[m] = wpos ? cw : -cw;
            key[m] = (((u64)ordf(tA[m])) << 6) | (u64)i;   // unique keys
            const bool crossed = key[m] < ky0;             // t_i "<" y0
            if (wpos == crossed) { Ap += ca; Bp += cw; }   // active at y0
            k0p += crossed ? 1.f : 0.f;
            keyU[sr * 66 + i] = key[m];                    // stride 66: bank-spread rows
        }
        const float k0f = sum16(k0p);            // segment index of y0
        const float Af  = sum16(Ap) + ba2[0];    // acc(y) = Af + Bf*y in segment k0
        const float Bf  = sum16(Bp);
        if (sl == 0) *(f32x4*)&initS[sr * 4] = f32x4{y0_s, k0f, Af, Bf};
    }
    __syncthreads();                               // B0: As1 + omg + keys + initS ready

    // ---- PWL setup part B: rank-sort (all-pairs on unique u64 keys), scatter
    {
        int rk[4] = {0, 0, 0, 0};
        const u64* krow = keyU + sr * 66;
        for (int j = 0; j < 64; j += 2) {
            const u64x2 kk = *(const u64x2*)&krow[j];
            #pragma unroll
            for (int m = 0; m < 4; ++m)
                rk[m] += (int)(kk.x < key[m]) + (int)(kk.y < key[m]);
        }
        __syncthreads();                           // S1: all rank reads done
        #pragma unroll
        for (int m = 0; m < 4; ++m) {
            const int idx = sr * 68 + 2 + rk[m];   // overwrites keyU region
            tS[idx] = tA[m];
            *(f32x2*)&dP[2 * idx] = f32x2{dAv[m], dBv[m]};
        }
        if (sl == 0) {                             // sentinel pads
            const int b = sr * 68;
            const float INFV = __builtin_inff();
            tS[b] = -INFV; tS[b + 1] = -INFV; tS[b + 66] = INFV; tS[b + 67] = INFV;
            const f32x2 z = {0.f, 0.f};
            *(f32x2*)&dP[2 * b] = z;          *(f32x2*)&dP[2 * (b + 1)] = z;
            *(f32x2*)&dP[2 * (b + 66)] = z;   *(f32x2*)&dP[2 * (b + 67)] = z;
        }
    }
    // (no barrier needed: tables not read until after B1..B4)

    // ---- MFMA phases: each wave owns 32 cols (2 n-tiles), full 32-row M.
    f32x4 acc[2][2];

    auto seed = [&](const float* bias) {
        #pragma unroll
        for (int nt = 0; nt < 2; ++nt) {
            const float b = bias[wid * 32 + nt * 16 + ln];
            acc[0][nt] = f32x4{b, b, b, b};
            acc[1][nt] = acc[0][nt];
        }
    };

    // A-frags from LDS; B-frags prefetched from global (L2-resident) into
    // registers up-front (16 independent 16B loads -> one batched vmcnt wait).
    auto run_stage = [&](const unsigned short* Ap, const unsigned short* wp) {
        s16x8 Bv0[8], Bv1[8];
        #pragma unroll
        for (int it = 0; it < 8; ++it) {
            const int kblk = (it >> 1) * 8 + (it & 1) * 4 + quad;
            Bv0[it] = *(const s16x8*)&wp[((size_t)(kblk * 256) + wid * 32 + ln) * 8];
            Bv1[it] = *(const s16x8*)&wp[((size_t)(kblk * 256) + wid * 32 + 16 + ln) * 8];
        }
        #pragma unroll
        for (int it = 0; it < 8; ++it) {
            const int kblk = (it >> 1) * 8 + (it & 1) * 4 + quad;
            const int f    = kblk & 7;
            s16x8 a0 = *(const s16x8*)&Ap[(kblk * 32 + (ln ^ f)) * 8];
            s16x8 a1 = *(const s16x8*)&Ap[(kblk * 32 + ((ln ^ f) + 16)) * 8];
            acc[0][0] = __builtin_amdgcn_mfma_f32_16x16x32_bf16(a0, Bv0[it], acc[0][0], 0, 0, 0);
            acc[1][0] = __builtin_amdgcn_mfma_f32_16x16x32_bf16(a1, Bv0[it], acc[1][0], 0, 0, 0);
            acc[0][1] = __builtin_amdgcn_mfma_f32_16x16x32_bf16(a0, Bv1[it], acc[0][1], 0, 0, 0);
            acc[1][1] = __builtin_amdgcn_mfma_f32_16x16x32_bf16(a1, Bv1[it], acc[1][1], 0, 0, 0);
        }
    };

    auto write_packed = [&](unsigned short* dst, bool addOm) {
        #pragma unroll
        for (int nt = 0; nt < 2; ++nt) {
            const int col = wid * 32 + nt * 16 + ln;
            const int kg  = col >> 3, f = kg & 7, jj = col & 7;
            const float wo = addOm ? w256g[col] : 0.f;
            #pragma unroll
            for (int mt = 0; mt < 2; ++mt) {
                #pragma unroll
                for (int r = 0; r < 4; ++r) {
                    const int row = mt * 16 + quad * 4 + r;
                    float v = acc[mt][nt][r];
                    if (addOm) v = fmaf(omg[row], wo, v);
                    v = fmaxf(v, 0.f);
                    dst[(kg * 32 + (row ^ f)) * 8 + jj] = f2bf(v);
                }
            }
        }
    };

    seed(bf1);
    run_stage(As1, wpack);
    write_packed(Hs, true);
    __syncthreads();                               // B1: Hs ready
    seed(bf2);
    run_stage(Hs, wpack + 65536);
    write_packed(As1, false);
    __syncthreads();                               // B2: As1(feat) ready
    seed(biasH);
    run_stage(As1, wpack + 131072);
    __syncthreads();                               // B3a: all waves done with As1/Hs (alias!)
    #pragma unroll
    for (int nt = 0; nt < 2; ++nt) {
        const int col = wid * 32 + nt * 16 + ln;
        #pragma unroll
        for (int mt = 0; mt < 2; ++mt) {
            #pragma unroll
            for (int r = 0; r < 4; ++r) {
                const int row = mt * 16 + quad * 4 + r;
                headsF[row * 256 + ((col + row * 8) & 255)] = fmaxf(acc[mt][nt][r], 0.f);
            }
        }
    }
    __syncthreads();                               // B3: heads ready

    // ---- 128-dot heads: 16 lanes/row -> xi
    {
        const int m = tid >> 4, l = tid & 15;
        float pm = 0.f, pl = 0.f;
        #pragma unroll
        for (int q = 0; q < 2; ++q) {
            const int c0 = l * 8 + q * 4;
            const float4 hm = *(const float4*)&headsF[m * 256 + ((c0 + m * 8) & 255)];
            const float4 wm = *(const float4*)&Wm2[c0];
            const float4 hl = *(const float4*)&headsF[m * 256 + ((128 + c0 + m * 8) & 255)];
            const float4 wl = *(const float4*)&Wl2[c0];
            pm = fmaf(hm.w, wm.w, fmaf(hm.z, wm.z, fmaf(hm.y, wm.y, fmaf(hm.x, wm.x, pm))));
            pl = fmaf(hl.w, wl.w, fmaf(hl.z, wl.z, fmaf(hl.y, wl.y, fmaf(hl.x, wl.x, pl))));
        }
        pm = sum16(pm);
        pl = sum16(pl);
        if (l == 0) {
            const float xm  = pm + bm2[0];
            const float mean = fmaxf(xm, 0.f) + log1pf(expf(-fabsf(xm)));
            const float lnv  = pl + bl2[0];
            out_mean[r0 + m]  = mean;
            out_lnvar[r0 + m] = lnv;
            float xi = mean + expf(0.5f * lnv) * eps_g[r0 + m];
            xiS[m] = fminf(fmaxf(xi, 0.f), 1.f);
        }
    }
    __syncthreads();                               // B4: xiS ready (last barrier)

    // ---- PWL ODE scan: wave 0 only, one LANE per row (32 lanes), others exit.
    // Euler on (y,v) == y_{t+2} = 2y_{t+1} - y_t + DT^2*acc(y_t).
    // Segment state + both neighbor deltas kept in registers; handler's LDS
    // loads are only needed at the *next* crossing (latency hidden).
    if (wid != 0) return;
    if (lane >= 32) return;
    {
        const int r = lane;
        const f32x4 ini = *(const f32x4*)&initS[r * 4];
        const float y0_s = ini.x;
        int   k    = (int)ini.y;
        float segA = ini.z, segB = ini.w;
        const float xi   = xiS[r];
        const float dfac = expf(-xi * DT_C);
        const float* tSr = tS + r * 68 + 2;
        const float* dPb = dP + (r * 68 + 2) * 2;
        float tLo  = tSr[k - 1], tHi = tSr[k], tHi2 = tSr[k + 1], tLo2 = tSr[k - 2];
        f32x2 dU = *(const f32x2*)&dPb[2 * k];
        f32x2 dD = *(const f32x2*)&dPb[2 * (k - 1)];
        float ym = y0_s, yc = y0_s;
        float pr = fmaf(segB, y0_s, segA);
        float d  = 1.f;
        const float DT2 = DT_C * DT_C;
        float* orow = xout + (size_t)(r0 + r) * 256;

        auto step = [&](float& dst) {
            if (__builtin_expect(yc >= tHi, 0)) {          // walk up
                do {
                    segA += dU.x; segB += dU.y;
                    dD = dU;
                    tLo2 = tLo; tLo = tHi; tHi = tHi2;
                    ++k;
                    tHi2 = tSr[k + 1];
                    dU = *(const f32x2*)&dPb[2 * k];
                } while (yc >= tHi);
            } else if (__builtin_expect(yc < tLo, 0)) {    // walk down
                do {
                    segA -= dD.x; segB -= dD.y;
                    dU = dD;
                    tHi2 = tHi; tHi = tLo; tLo = tLo2;
                    --k;
                    tLo2 = tSr[k - 2];
                    dD = *(const f32x2*)&dPb[2 * (k - 1)];
                } while (yc < tLo);
            }
            const float pn = fmaf(segB, yc, segA);         // acc(y_{t+1})
            dst = ym * d;                                  // decayed output y_t*e^{-xi*t*DT}
            d *= dfac;
            const float yn = fmaf(DT2, pr, fmaf(2.f, yc, -ym));
            ym = yc; yc = yn; pr = pn;
        };

        for (int g = 0; g < 64; ++g) {
            float4 cv;
            step(cv.x); step(cv.y); step(cv.z); step(cv.w);
            *(float4*)&orow[g * 4] = cv;
        }
    }
}

// ---------------------------------------------------------------------------
extern "C" void kernel_launch(void* const* d_in, const int* in_sizes, int n_in,
                              void* d_out, int out_size, void* d_ws, size_t ws_size,
                              hipStream_t stream)
{
    const float* data    = (const float*)d_in[0];
    const float* omega   = (const float*)d_in[1];
    const float* eps     = (const float*)d_in[2];
    const float* W_feat1 = (const float*)d_in[3];
    const float* b_feat1 = (const float*)d_in[4];
    const float* W_feat2 = (const float*)d_in[5];
    const float* b_feat2 = (const float*)d_in[6];
    const float* W_xim1  = (const float*)d_in[7];
    const float* b_xim1  = (const float*)d_in[8];
    const float* W_xim2  = (const float*)d_in[9];
    const float* b_xim2  = (const float*)d_in[10];
    const float* W_xil1  = (const float*)d_in[11];
    const float* b_xil1  = (const float*)d_in[12];
    const float* W_xil2  = (const float*)d_in[13];
    const float* b_xil2  = (const float*)d_in[14];
    const float* W_aux1  = (const float*)d_in[15];
    const float* b_aux1  = (const float*)d_in[16];
    const float* W_aux2  = (const float*)d_in[17];
    const float* b_aux2  = (const float*)d_in[18];

    float* out_mean  = (float*)d_out;
    float* out_lnvar = out_mean + NROWS;
    float* out_x     = out_lnvar + NROWS;

    unsigned short* wpack = (unsigned short*)d_ws;           // 384KB bf16
    float* biasH = (float*)((char*)d_ws + 3 * 32 * 256 * 8 * 2);

    prep_k<<<96, 256, 0, stream>>>(W_feat1, W_feat2, W_xim1, W_xil1,
                                   b_xim1, b_xil1, wpack, biasH);
    fused_k<<<512, 512, 0, stream>>>(data, omega, eps, wpack, biasH,
                                     b_feat1, b_feat2, W_feat1 + 256 * 256,
                                     W_xim2, b_xim2, W_xil2, b_xil2,
                                     W_aux1, b_aux1, W_aux2, b_aux2,
                                     out_mean, out_lnvar, out_x);
}

// Round 4
// 142.037 us; speedup vs baseline: 1.0508x; 1.0508x over previous
//
#include <hip/hip_runtime.h>
#include <math.h>

#define NROWS 16384
#define DT_C 0.01f

typedef short s16x8 __attribute__((ext_vector_type(8)));
typedef float f32x4 __attribute__((ext_vector_type(4)));
typedef float f32x2 __attribute__((ext_vector_type(2)));

__device__ __forceinline__ unsigned short f2bf(float f) {
    unsigned u = __float_as_uint(f);
    u += 0x7fffu + ((u >> 16) & 1u);
    return (unsigned short)(u >> 16);
}
__device__ __forceinline__ unsigned pack2bf(float a, float b) {
    return (unsigned)f2bf(a) | ((unsigned)f2bf(b) << 16);
}
// VALU-pipe cross-lane adds via DPP (no LDS pipe). 8-lane sum:
// xor1 (0xB1), xor2 (0x4E), row_half_mirror (0x141).
template <int CTRL>
__device__ __forceinline__ float dppadd(float v) {
    int x = __builtin_amdgcn_update_dpp(0, __float_as_int(v), CTRL, 0xF, 0xF, true);
    return v + __int_as_float(x);
}
__device__ __forceinline__ float sum8(float p) {
    p = dppadd<0xB1>(p);
    p = dppadd<0x4E>(p);
    p = dppadd<0x141>(p);
    return p;
}

// ---------------------------------------------------------------------------
// Prep: pack stage-B weights to bf16 flat [stage][k8][n][8] (k = k8*8+j).
// s=0: W_feat1[0:256], s=1: W_feat2, s=2: [W_xim1 | W_xil1].
// ---------------------------------------------------------------------------
__global__ __launch_bounds__(256) void prep_k(
    const float* __restrict__ Wf1, const float* __restrict__ Wf2,
    const float* __restrict__ Wm1, const float* __restrict__ Wl1,
    const float* __restrict__ bm1, const float* __restrict__ bl1,
    unsigned short* __restrict__ wpack, float* __restrict__ biasH)
{
    const int id = blockIdx.x * 256 + threadIdx.x;   // 0..24575
    const int n  = id & 255;
    const int k8 = (id >> 8) & 31;
    const int s  = id >> 13;

    unsigned short tmp[8];
    #pragma unroll
    for (int j = 0; j < 8; ++j) {
        const int k = k8 * 8 + j;
        float v;
        if (s == 0)      v = Wf1[k * 256 + n];
        else if (s == 1) v = Wf2[k * 256 + n];
        else             v = (n < 128) ? Wm1[k * 128 + n] : Wl1[k * 128 + n - 128];
        tmp[j] = f2bf(v);
    }
    *(uint4*)&wpack[((s * 32 + k8) * 256 + n) * 8] = *(const uint4*)tmp;

    if (id < 256) biasH[id] = (id < 128) ? bm1[id] : bl1[id - 128];
}

// ---------------------------------------------------------------------------
// Fused kernel, 512 threads (8 waves) per 32-row block, wave-specialized:
//   waves 4-7: ODE scan (xi-independent, branchless DPP-MLP, raw y -> xout),
//              started immediately, signal done-flag, exit.
//   waves 0-3: stage data->LDS frags; MFMA h1->feat->heads; 128-dots -> xi;
//              wait for scan; decay epilogue on L2-hot xout rows.
//   Inter-phase sync among waves 0-3 via LDS atomic counters (no s_barrier
//   after the first one, since scan waves diverge).
// ---------------------------------------------------------------------------
__global__ __launch_bounds__(512, 4) void fused_k(
    const float* __restrict__ data, const float* __restrict__ omega,
    const float* __restrict__ eps_g,
    const unsigned short* __restrict__ wpack, const float* __restrict__ biasH,
    const float* __restrict__ bf1, const float* __restrict__ bf2,
    const float* __restrict__ w256g,
    const float* __restrict__ Wm2, const float* __restrict__ bm2,
    const float* __restrict__ Wl2, const float* __restrict__ bl2,
    const float* __restrict__ Wa1, const float* __restrict__ ba1,
    const float* __restrict__ Wa2, const float* __restrict__ ba2,
    float* __restrict__ out_mean, float* __restrict__ out_lnvar,
    float* __restrict__ xout)
{
    // 32.25KB LDS: headsF aliases As1+Hs (dead by heads phase)
    __shared__ __align__(16) unsigned char smem[33024];
    __shared__ int syncc[8];
    unsigned short* As1 = (unsigned short*)smem;            // 16KB frags: data, then feat
    unsigned short* Hs  = (unsigned short*)(smem + 16384);  // 16KB frags: h1
    float* headsF = (float*)smem;                           // 32KB alias: heads f32
    float* omg = (float*)(smem + 32768);
    float* xiS = omg + 32;

    const int tid  = threadIdx.x;
    const int wid  = tid >> 6;
    const int lane = tid & 63;
    const int ln   = lane & 15;
    const int quad = lane >> 4;
    const int r0   = blockIdx.x * 32;

    if (tid < 8) syncc[tid] = 0;
    __syncthreads();                     // the ONLY full-block barrier

    // =======================================================================
    // SCAN WAVES (4..7): fully independent of the MFMA side.
    // =======================================================================
    if (wid >= 4) {
        const int st  = tid - 256;       // 0..255
        const int r   = st >> 3;         // row 0..31
        const int l   = st & 7;          // 8 lanes/row
        const int row = r0 + r;
        const float om = omega[row];
        const float pseed = ba2[0] * 0.125f;

        f32x2 w1v[4], Av[4], w2v[4];
        #pragma unroll
        for (int i = 0; i < 4; ++i) {
            const f32x2 w0 = *(const f32x2*)&Wa1[l * 8 + i * 2];
            const f32x2 bb = *(const f32x2*)&ba1[l * 8 + i * 2];
            w1v[i] = *(const f32x2*)&Wa1[64 + l * 8 + i * 2];
            w2v[i] = *(const f32x2*)&Wa2[l * 8 + i * 2];
            Av[i]  = f32x2{fmaf(om, w0.x, bb.x), fmaf(om, w0.y, bb.y)};
        }

        auto partial = [&](float y) -> float {
            const f32x2 y2 = f32x2{y, y};
            f32x2 acc2 = f32x2{pseed, 0.f};
            #pragma unroll
            for (int i = 0; i < 4; ++i) {
                f32x2 h = __builtin_elementwise_fma(y2, w1v[i], Av[i]);
                h = __builtin_elementwise_max(h, f32x2{0.f, 0.f});
                acc2 = __builtin_elementwise_fma(h, w2v[i], acc2);
            }
            return acc2.x + acc2.y;
        };

        const float y0 = data[(size_t)row * 256];
        float ym = y0;          // y_t
        float yc = y0;          // y_{t+1}  (v0 = 0)
        const float DT2 = DT_C * DT_C;
        float pr = sum8(partial(ym));

        float* orow = xout + (size_t)row * 256 + l * 4;
        for (int tb = 0; tb < 8; ++tb) {
            float cur[4];
            #pragma unroll
            for (int j = 0; j < 32; ++j) {
                if ((j >> 2) == l) cur[j & 3] = ym;    // compile-time index
                float pn = sum8(partial(yc));
                const float ynext = fmaf(DT2, pr, fmaf(2.f, yc, -ym));
                ym = yc; yc = ynext; pr = pn;          // pr consumed next step
            }
            *(float4*)&orow[tb * 32] = *(const float4*)cur;   // raw (undecayed)
        }

        __threadfence_block();           // drain stores (vmcnt) before signal
        if (lane == 0) atomicAdd(&syncc[6], 1);
        return;
    }

    // =======================================================================
    // MFMA WAVES (0..3), tid 0..255
    // =======================================================================
    auto fsync = [&](int slot) {         // sync among the 4 MFMA waves
        __threadfence_block();
        if (lane == 0) atomicAdd(&syncc[slot], 1);
        while (*(volatile int*)&syncc[slot] < 4) __builtin_amdgcn_s_sleep(2);
        __threadfence_block();
    };

    // ---- stage data -> As1 (coalesced, swizzled frag pack)
    {
        #pragma unroll
        for (int g2 = 0; g2 < 8; ++g2) {
            const int unit = g2 * 256 + tid;     // 16B unit over 32x256 f32
            const int m    = unit >> 6;
            const int c16  = unit & 63;
            const int kblk = c16 >> 1;
            const int h    = c16 & 1;
            const float4 v = *(const float4*)&data[(size_t)(r0 + m) * 256 + c16 * 4];
            unsigned* d = (unsigned*)&As1[((kblk * 32) + (m ^ (kblk & 7))) * 8 + h * 4];
            d[0] = pack2bf(v.x, v.y);
            d[1] = pack2bf(v.z, v.w);
        }
        if (tid < 32) omg[tid] = omega[r0 + tid];
    }
    fsync(0);                                      // B0: As1 + omg ready

    // ---- MFMA phases
    f32x4 acc[2][4];

    auto seed = [&](const float* bias) {
        #pragma unroll
        for (int nt = 0; nt < 4; ++nt) {
            const float b = bias[wid * 64 + nt * 16 + ln];
            acc[0][nt] = f32x4{b, b, b, b};
            acc[1][nt] = acc[0][nt];
        }
    };

    // A-frags from LDS, B-frags straight from global (L2-resident)
    auto run_stage = [&](const unsigned short* Ap, const unsigned short* wp) {
        #pragma unroll
        for (int c = 0; c < 4; ++c) {
            #pragma unroll
            for (int kk = 0; kk < 2; ++kk) {
                const int kb   = kk * 4 + quad;
                const int kblk = c * 8 + kb;
                const int f    = kblk & 7;
                s16x8 b0 = *(const s16x8*)&wp[((size_t)(kblk * 256) + wid * 64 + 0 * 16 + ln) * 8];
                s16x8 b1 = *(const s16x8*)&wp[((size_t)(kblk * 256) + wid * 64 + 1 * 16 + ln) * 8];
                s16x8 b2 = *(const s16x8*)&wp[((size_t)(kblk * 256) + wid * 64 + 2 * 16 + ln) * 8];
                s16x8 b3 = *(const s16x8*)&wp[((size_t)(kblk * 256) + wid * 64 + 3 * 16 + ln) * 8];
                s16x8 a0 = *(const s16x8*)&Ap[(kblk * 32 + (ln ^ f)) * 8];
                s16x8 a1 = *(const s16x8*)&Ap[(kblk * 32 + ((ln ^ f) + 16)) * 8];
                acc[0][0] = __builtin_amdgcn_mfma_f32_16x16x32_bf16(a0, b0, acc[0][0], 0, 0, 0);
                acc[1][0] = __builtin_amdgcn_mfma_f32_16x16x32_bf16(a1, b0, acc[1][0], 0, 0, 0);
                acc[0][1] = __builtin_amdgcn_mfma_f32_16x16x32_bf16(a0, b1, acc[0][1], 0, 0, 0);
                acc[1][1] = __builtin_amdgcn_mfma_f32_16x16x32_bf16(a1, b1, acc[1][1], 0, 0, 0);
                acc[0][2] = __builtin_amdgcn_mfma_f32_16x16x32_bf16(a0, b2, acc[0][2], 0, 0, 0);
                acc[1][2] = __builtin_amdgcn_mfma_f32_16x16x32_bf16(a1, b2, acc[1][2], 0, 0, 0);
                acc[0][3] = __builtin_amdgcn_mfma_f32_16x16x32_bf16(a0, b3, acc[0][3], 0, 0, 0);
                acc[1][3] = __builtin_amdgcn_mfma_f32_16x16x32_bf16(a1, b3, acc[1][3], 0, 0, 0);
            }
        }
    };

    auto write_packed = [&](unsigned short* dst, bool addOm) {
        #pragma unroll
        for (int nt = 0; nt < 4; ++nt) {
            const int col = wid * 64 + nt * 16 + ln;
            const int kg  = col >> 3, f = kg & 7, jj = col & 7;
            const float wo = addOm ? w256g[col] : 0.f;
            #pragma unroll
            for (int mt = 0; mt < 2; ++mt) {
                #pragma unroll
                for (int r = 0; r < 4; ++r) {
                    const int row = mt * 16 + quad * 4 + r;
                    float v = acc[mt][nt][r];
                    if (addOm) v = fmaf(omg[row], wo, v);
                    v = fmaxf(v, 0.f);
                    dst[(kg * 32 + (row ^ f)) * 8 + jj] = f2bf(v);
                }
            }
        }
    };

    seed(bf1);
    run_stage(As1, wpack);
    write_packed(Hs, true);
    fsync(1);                                      // B1: Hs ready
    seed(bf2);
    run_stage(Hs, wpack + 65536);
    write_packed(As1, false);
    fsync(2);                                      // B2: As1(feat) ready
    seed(biasH);
    run_stage(As1, wpack + 131072);
    fsync(3);                                      // B3a: done with As1/Hs (alias!)
    #pragma unroll
    for (int nt = 0; nt < 4; ++nt) {
        const int col = wid * 64 + nt * 16 + ln;
        #pragma unroll
        for (int mt = 0; mt < 2; ++mt) {
            #pragma unroll
            for (int r = 0; r < 4; ++r) {
                const int row = mt * 16 + quad * 4 + r;
                headsF[row * 256 + ((col + row * 8) & 255)] = fmaxf(acc[mt][nt][r], 0.f);
            }
        }
    }
    fsync(4);                                      // B3: heads ready

    // ---- 128-dot heads: 8 lanes/row -> xi
    {
        const int m = tid >> 3, l = tid & 7;
        float pm = 0.f, pl = 0.f;
        #pragma unroll
        for (int q = 0; q < 4; ++q) {
            const int c0 = l * 16 + q * 4;
            const float4 hm = *(const float4*)&headsF[m * 256 + ((c0 + m * 8) & 255)];
            const float4 wm = *(const float4*)&Wm2[c0];
            const float4 hl = *(const float4*)&headsF[m * 256 + ((128 + c0 + m * 8) & 255)];
            const float4 wl = *(const float4*)&Wl2[c0];
            pm = fmaf(hm.w, wm.w, fmaf(hm.z, wm.z, fmaf(hm.y, wm.y, fmaf(hm.x, wm.x, pm))));
            pl = fmaf(hl.w, wl.w, fmaf(hl.z, wl.z, fmaf(hl.y, wl.y, fmaf(hl.x, wl.x, pl))));
        }
        pm = sum8(pm);
        pl = sum8(pl);
        if (l == 0) {
            const float xm  = pm + bm2[0];
            const float mean = fmaxf(xm, 0.f) + log1pf(expf(-fabsf(xm)));
            const float lnv  = pl + bl2[0];
            out_mean[r0 + m]  = mean;
            out_lnvar[r0 + m] = lnv;
            float xi = mean + expf(0.5f * lnv) * eps_g[r0 + m];
            xiS[m] = fminf(fmaxf(xi, 0.f), 1.f);
        }
    }
    fsync(5);                                      // B4: xiS ready

    // ---- wait for scan waves' raw y (same block -> same CU/L2)
    while (*(volatile int*)&syncc[6] < 4) __builtin_amdgcn_s_sleep(2);
    __threadfence_block();

    // ---- epilogue: apply decay in place (xout rows are L2-hot, 33KB/block)
    {
        const int r   = tid >> 3;
        const int l   = tid & 7;
        const float nxdt = -xiS[r] * DT_C;
        float* orow = xout + (size_t)(r0 + r) * 256 + l * 4;
        #pragma unroll
        for (int tb = 0; tb < 8; ++tb) {
            float4 v = *(const float4*)&orow[tb * 32];
            const int c0 = tb * 32 + l * 4;
            v.x *= __expf(nxdt * (float)(c0 + 0));
            v.y *= __expf(nxdt * (float)(c0 + 1));
            v.z *= __expf(nxdt * (float)(c0 + 2));
            v.w *= __expf(nxdt * (float)(c0 + 3));
            *(float4*)&orow[tb * 32] = v;
        }
    }
}

// ---------------------------------------------------------------------------
extern "C" void kernel_launch(void* const* d_in, const int* in_sizes, int n_in,
                              void* d_out, int out_size, void* d_ws, size_t ws_size,
                              hipStream_t stream)
{
    const float* data    = (const float*)d_in[0];
    const float* omega   = (const float*)d_in[1];
    const float* eps     = (const float*)d_in[2];
    const float* W_feat1 = (const float*)d_in[3];
    const float* b_feat1 = (const float*)d_in[4];
    const float* W_feat2 = (const float*)d_in[5];
    const float* b_feat2 = (const float*)d_in[6];
    const float* W_xim1  = (const float*)d_in[7];
    const float* b_xim1  = (const float*)d_in[8];
    const float* W_xim2  = (const float*)d_in[9];
    const float* b_xim2  = (const float*)d_in[10];
    const float* W_xil1  = (const float*)d_in[11];
    const float* b_xil1  = (const float*)d_in[12];
    const float* W_xil2  = (const float*)d_in[13];
    const float* b_xil2  = (const float*)d_in[14];
    const float* W_aux1  = (const float*)d_in[15];
    const float* b_aux1  = (const float*)d_in[16];
    const float* W_aux2  = (const float*)d_in[17];
    const float* b_aux2  = (const float*)d_in[18];

    float* out_mean  = (float*)d_out;
    float* out_lnvar = out_mean + NROWS;
    float* out_x     = out_lnvar + NROWS;

    unsigned short* wpack = (unsigned short*)d_ws;           // 384KB bf16
    float* biasH = (float*)((char*)d_ws + 3 * 32 * 256 * 8 * 2);

    prep_k<<<96, 256, 0, stream>>>(W_feat1, W_feat2, W_xim1, W_xil1,
                                   b_xim1, b_xil1, wpack, biasH);
    fused_k<<<512, 512, 0, stream>>>(data, omega, eps, wpack, biasH,
                                     b_feat1, b_feat2, W_feat1 + 256 * 256,
                                     W_xim2, b_xim2, W_xil2, b_xil2,
                                     W_aux1, b_aux1, W_aux2, b_aux2,
                                     out_mean, out_lnvar, out_x);
}